// Round 1
// baseline (1091.712 us; speedup 1.0000x reference)
//
#include <hip/hip_runtime.h>

#define Bb 2
#define Cc 1024
#define CIi 512
#define Nn 6272
#define SCALE (1.0f / 32.0f)

typedef __bf16 bf16;
typedef __bf16 bf16x8 __attribute__((ext_vector_type(8)));
typedef __bf16 bf16x4 __attribute__((ext_vector_type(4)));
typedef float f32x4 __attribute__((ext_vector_type(4)));
typedef unsigned int u32x4 __attribute__((ext_vector_type(4)));

// ---------------------------------------------------------------------------
// Kernel 1: x (B,C,N) fp32 -> xT (B,N,C) bf16  (LDS tile transpose)
// ---------------------------------------------------------------------------
__global__ __launch_bounds__(256) void xpose_kernel(const float* __restrict__ x,
                                                    bf16* __restrict__ xT) {
  __shared__ float tile[32][33];
  int b = blockIdx.z;
  int n0 = blockIdx.x * 32, c0 = blockIdx.y * 32;
  int tn = threadIdx.x & 31, tr = threadIdx.x >> 5;
  const float* xp = x + ((size_t)b * Cc + c0) * Nn + n0;
  for (int i = 0; i < 4; i++) {
    int c = tr + i * 8;
    tile[c][tn] = xp[(size_t)c * Nn + tn];
  }
  __syncthreads();
  bf16* op = xT + ((size_t)b * Nn + n0) * Cc + c0;
  for (int i = 0; i < 4; i++) {
    int n = tr + i * 8;
    op[(size_t)n * Cc + tn] = (bf16)tile[tn][n];
  }
}

// ---------------------------------------------------------------------------
// Kernel 2: fused QKV projection.
//   kT,qT: (B,N,CI) bf16  (n-major, d contiguous)
//   v    : (B,CI,N) bf16  (d-major, n contiguous)  -> PV B-frags contiguous
// MFMA roles: m = n-position, n = d, k = c.  Tile 128x128, BK=32, 4 waves.
// ---------------------------------------------------------------------------
__global__ __launch_bounds__(256) void proj_kernel(
    const bf16* __restrict__ xT, const float* __restrict__ Wk,
    const float* __restrict__ Wq, const float* __restrict__ Wv,
    const float* __restrict__ bk, const float* __restrict__ bq,
    const float* __restrict__ bv, bf16* __restrict__ kT, bf16* __restrict__ qT,
    bf16* __restrict__ vv) {
  int z = blockIdx.z;
  int b = z / 3, proj = z % 3;
  const float* W = proj == 0 ? Wk : (proj == 1 ? Wq : Wv);
  const float* bias = proj == 0 ? bk : (proj == 1 ? bq : bv);
  int m0 = blockIdx.x * 128;  // n-position tile
  int d0 = blockIdx.y * 128;  // output-channel tile
  __shared__ __align__(16) bf16 la[128 * 40];  // xT tile [n][c], pad 40 (2-way only)
  __shared__ __align__(16) bf16 lb[128 * 40];  // W  tile [d][c]
  int tid = threadIdx.x;
  int wave = tid >> 6, lane = tid & 63, quad = lane >> 4, l16 = lane & 15;
  int wm = (wave >> 1) * 64, wn = (wave & 1) * 64;
  int row2 = tid >> 1, half = tid & 1;

  f32x4 acc[4][4] = {};
  const bf16* aSrc = xT + ((size_t)b * Nn + m0) * Cc;
  const float* bSrc = W + (size_t)(d0 + row2) * Cc;

  for (int k0 = 0; k0 < Cc; k0 += 32) {
    const u32x4* ga = (const u32x4*)(aSrc + (size_t)row2 * Cc + k0 + half * 16);
    u32x4 a0 = ga[0], a1 = ga[1];
    const f32x4* gb = (const f32x4*)(bSrc + k0 + half * 16);
    f32x4 w0 = gb[0], w1 = gb[1], w2 = gb[2], w3 = gb[3];
    *(u32x4*)&la[row2 * 40 + half * 16] = a0;
    *(u32x4*)&la[row2 * 40 + half * 16 + 8] = a1;
    bf16x8 p0 = {(bf16)w0[0], (bf16)w0[1], (bf16)w0[2], (bf16)w0[3],
                 (bf16)w1[0], (bf16)w1[1], (bf16)w1[2], (bf16)w1[3]};
    bf16x8 p1 = {(bf16)w2[0], (bf16)w2[1], (bf16)w2[2], (bf16)w2[3],
                 (bf16)w3[0], (bf16)w3[1], (bf16)w3[2], (bf16)w3[3]};
    *(bf16x8*)&lb[row2 * 40 + half * 16] = p0;
    *(bf16x8*)&lb[row2 * 40 + half * 16 + 8] = p1;
    __syncthreads();
    bf16x8 af[4], bfr[4];
    for (int t = 0; t < 4; t++)
      af[t] = *(const bf16x8*)&la[(wm + t * 16 + l16) * 40 + quad * 8];
    for (int t = 0; t < 4; t++)
      bfr[t] = *(const bf16x8*)&lb[(wn + t * 16 + l16) * 40 + quad * 8];
    for (int tm = 0; tm < 4; tm++)
      for (int tn = 0; tn < 4; tn++)
        acc[tm][tn] = __builtin_amdgcn_mfma_f32_16x16x32_bf16(
            af[tm], bfr[tn], acc[tm][tn], 0, 0, 0);
    __syncthreads();
  }
  // C/D layout: col = lane&15, row = quad*4 + r   (verified m89)
  for (int tn = 0; tn < 4; tn++) {
    int dcol = d0 + wn + tn * 16 + l16;
    float bval = bias[dcol];
    for (int tm = 0; tm < 4; tm++) {
      int nbase = m0 + wm + tm * 16 + quad * 4;
      for (int r = 0; r < 4; r++) {
        float val = acc[tm][tn][r] + bval;
        int nrow = nbase + r;
        if (proj == 0)
          kT[((size_t)b * Nn + nrow) * CIi + dcol] = (bf16)val;
        else if (proj == 1)
          qT[((size_t)b * Nn + nrow) * CIi + dcol] = (bf16)val;
        else
          vv[((size_t)b * CIi + dcol) * Nn + nrow] = (bf16)val;
      }
    }
  }
}

// ---------------------------------------------------------------------------
// Kernel 3: flash attention. Block = 32 i-rows, 4 waves.
//   S[i][j] = (1/32) * sum_d kT[i][d] qT[j][d];  online softmax over j;
//   O[i][d] += P[i][j] v[d][j].
// Waves: S-phase -> quadrant (ih=w>>1, jh=w&1); PV-phase -> d-chunk w*128.
// K frags in registers; Q tile in LDS (XOR-swizzled 16B chunks);
// V frags read straight from global (contiguous in (CI,N) layout).
// ---------------------------------------------------------------------------
__global__ __launch_bounds__(256) void attn_kernel(const bf16* __restrict__ kT,
                                                   const bf16* __restrict__ qT,
                                                   const bf16* __restrict__ vv,
                                                   bf16* __restrict__ y) {
  int b = blockIdx.y;
  int i0 = blockIdx.x * 32;
  int tid = threadIdx.x;
  int wave = tid >> 6, lane = tid & 63, quad = lane >> 4, l16 = lane & 15;
  int ih = wave >> 1, jh = wave & 1;
  int dw = wave * 128;

  __shared__ __align__(16) bf16 lq[32 * 512];  // q tile, swizzled
  __shared__ __align__(16) float sm[32 * 36];  // S fp32; P bf16 overlaid per row
  __shared__ float red[96];                    // m, l, corr
  float* lm = red;
  float* ll = red + 32;
  float* lcorr = red + 64;

  // K fragments: A-layout A[m=lane&15][k=quad*8+j], 16 k-chunks of 32
  bf16x8 kf[16];
  {
    const bf16* kp =
        kT + ((size_t)b * Nn + i0 + ih * 16 + l16) * CIi + quad * 8;
    for (int kk = 0; kk < 16; kk++) kf[kk] = *(const bf16x8*)(kp + kk * 32);
  }
  f32x4 oacc[2][8] = {};
  if (tid < 32) {
    lm[tid] = -1e30f;
    ll[tid] = 0.0f;
  }
  __syncthreads();

  const bf16* qb = qT + (size_t)b * Nn * CIi;
  const bf16* vb = vv + (size_t)b * CIi * Nn;

  for (int j0 = 0; j0 < Nn; j0 += 32) {
    // stage q tile: 32 rows x 512 bf16; 16B chunk u stored at u^(j&7)
    for (int it = 0; it < 8; it++) {
      int idx = tid + it * 256;
      int j = idx >> 6, u = idx & 63;
      u32x4 qd = *(const u32x4*)(qb + (size_t)(j0 + j) * CIi + u * 8);
      *(u32x4*)&lq[j * 512 + ((u ^ (j & 7)) * 8)] = qd;
    }
    __syncthreads();
    // V fragments (global, 16B contiguous); latency hidden by S compute
    u32x4 vf[8];
    for (int dt = 0; dt < 8; dt++)
      vf[dt] =
          *(const u32x4*)(vb + (size_t)(dw + dt * 16 + l16) * Nn + j0 + quad * 8);
    // S quadrant: 16 MFMAs over d=512
    f32x4 s = {};
    {
      int jrow = jh * 16 + l16;
      const bf16* qrow = &lq[jrow * 512];
      int jx = jrow & 7;
      for (int kk = 0; kk < 16; kk++) {
        int u = kk * 4 + quad;
        bf16x8 qf = *(const bf16x8*)(qrow + ((u ^ jx) * 8));
        s = __builtin_amdgcn_mfma_f32_16x16x32_bf16(kf[kk], qf, s, 0, 0, 0);
      }
    }
    for (int r = 0; r < 4; r++)
      sm[(ih * 16 + quad * 4 + r) * 36 + jh * 16 + l16] = s[r] * SCALE;
    __syncthreads();
    // online softmax: thread -> (row = tid>>3, 4 cols at seg*4); row-group of 8
    // lanes lives inside one wave, so shfl_xor(1,2,4) reduces it.
    {
      int row = tid >> 3, seg = tid & 7;
      f32x4 sv = *(const f32x4*)&sm[row * 36 + seg * 4];
      float mx = fmaxf(fmaxf(sv[0], sv[1]), fmaxf(sv[2], sv[3]));
      for (int o = 1; o < 8; o <<= 1) mx = fmaxf(mx, __shfl_xor(mx, o));
      float mold = lm[row];
      float mnew = fmaxf(mold, mx);
      float p0 = __expf(sv[0] - mnew);
      float p1 = __expf(sv[1] - mnew);
      float p2 = __expf(sv[2] - mnew);
      float p3 = __expf(sv[3] - mnew);
      float psum = (p0 + p1) + (p2 + p3);
      for (int o = 1; o < 8; o <<= 1) psum += __shfl_xor(psum, o);
      float corr = __expf(mold - mnew);
      if (seg == 0) {
        lm[row] = mnew;
        ll[row] = ll[row] * corr + psum;
        lcorr[row] = corr;
      }
      // P (bf16) overlaid on S rows (144B stride). Safe: p depends on sv, so
      // the store can't be scheduled before the load; wave is lockstep.
      bf16x4 pv4 = {(bf16)p0, (bf16)p1, (bf16)p2, (bf16)p3};
      *(bf16x4*)((char*)sm + row * 144 + seg * 8) = pv4;
    }
    __syncthreads();
    // PV: rescale O by corr, then 16 MFMAs (k = 32 j's in one shot)
    float cr[2][4];
    for (int it2 = 0; it2 < 2; it2++)
      for (int r = 0; r < 4; r++) cr[it2][r] = lcorr[it2 * 16 + quad * 4 + r];
    bf16x8 pf[2];
    for (int it2 = 0; it2 < 2; it2++)
      pf[it2] = *(const bf16x8*)((char*)sm + (it2 * 16 + l16) * 144 + quad * 16);
    for (int it2 = 0; it2 < 2; it2++)
      for (int dt = 0; dt < 8; dt++) {
        f32x4 a = oacc[it2][dt];
        for (int r = 0; r < 4; r++) a[r] *= cr[it2][r];
        oacc[it2][dt] = __builtin_amdgcn_mfma_f32_16x16x32_bf16(
            pf[it2], __builtin_bit_cast(bf16x8, vf[dt]), a, 0, 0, 0);
      }
    __syncthreads();
  }
  if (tid < 32) lcorr[tid] = 1.0f / ll[tid];
  __syncthreads();
  for (int it2 = 0; it2 < 2; it2++) {
    float inv[4];
    for (int r = 0; r < 4; r++) inv[r] = lcorr[it2 * 16 + quad * 4 + r];
    for (int dt = 0; dt < 8; dt++)
      for (int r = 0; r < 4; r++) {
        float val = oacc[it2][dt][r] * inv[r];
        y[((size_t)b * Nn + i0 + it2 * 16 + quad * 4 + r) * CIi + dw + dt * 16 +
          l16] = (bf16)val;
      }
  }
}

// ---------------------------------------------------------------------------
// Kernel 4: out = Wo(1024x512) @ y + bo + x.  m = dout, n = n-position, k = d.
// ---------------------------------------------------------------------------
__global__ __launch_bounds__(256) void out_kernel(
    const bf16* __restrict__ y, const float* __restrict__ Wo,
    const float* __restrict__ bo, const float* __restrict__ x,
    float* __restrict__ out) {
  int b = blockIdx.z;
  int d0 = blockIdx.x * 128;
  int m0 = blockIdx.y * 128;
  __shared__ __align__(16) bf16 la[128 * 40];  // Wo tile [dout][d]
  __shared__ __align__(16) bf16 lb[128 * 40];  // y  tile [npos][d]
  int tid = threadIdx.x;
  int wave = tid >> 6, lane = tid & 63, quad = lane >> 4, l16 = lane & 15;
  int wm = (wave >> 1) * 64, wn = (wave & 1) * 64;
  int row2 = tid >> 1, half = tid & 1;
  f32x4 acc[4][4] = {};
  const float* aSrc = Wo + (size_t)(d0 + row2) * CIi;
  const bf16* bSrc = y + ((size_t)b * Nn + m0 + row2) * CIi;
  for (int k0 = 0; k0 < CIi; k0 += 32) {
    const f32x4* ga = (const f32x4*)(aSrc + k0 + half * 16);
    f32x4 w0 = ga[0], w1 = ga[1], w2 = ga[2], w3 = ga[3];
    const u32x4* gb = (const u32x4*)(bSrc + k0 + half * 16);
    u32x4 b0 = gb[0], b1 = gb[1];
    bf16x8 p0 = {(bf16)w0[0], (bf16)w0[1], (bf16)w0[2], (bf16)w0[3],
                 (bf16)w1[0], (bf16)w1[1], (bf16)w1[2], (bf16)w1[3]};
    bf16x8 p1 = {(bf16)w2[0], (bf16)w2[1], (bf16)w2[2], (bf16)w2[3],
                 (bf16)w3[0], (bf16)w3[1], (bf16)w3[2], (bf16)w3[3]};
    *(bf16x8*)&la[row2 * 40 + half * 16] = p0;
    *(bf16x8*)&la[row2 * 40 + half * 16 + 8] = p1;
    *(u32x4*)&lb[row2 * 40 + half * 16] = b0;
    *(u32x4*)&lb[row2 * 40 + half * 16 + 8] = b1;
    __syncthreads();
    bf16x8 af[4], bfr[4];
    for (int t = 0; t < 4; t++)
      af[t] = *(const bf16x8*)&la[(wm + t * 16 + l16) * 40 + quad * 8];
    for (int t = 0; t < 4; t++)
      bfr[t] = *(const bf16x8*)&lb[(wn + t * 16 + l16) * 40 + quad * 8];
    for (int tm = 0; tm < 4; tm++)
      for (int tn = 0; tn < 4; tn++)
        acc[tm][tn] = __builtin_amdgcn_mfma_f32_16x16x32_bf16(
            af[tm], bfr[tn], acc[tm][tn], 0, 0, 0);
    __syncthreads();
  }
  for (int tm = 0; tm < 4; tm++) {
    for (int r = 0; r < 4; r++) {
      int drow = d0 + wm + tm * 16 + quad * 4 + r;
      float bval = bo[drow];
      const float* xrow = x + ((size_t)b * Cc + drow) * Nn;
      float* orow = out + ((size_t)b * Cc + drow) * Nn;
      for (int tn = 0; tn < 4; tn++) {
        int ncol = m0 + wn + tn * 16 + l16;
        orow[ncol] = acc[tm][tn][r] + bval + xrow[ncol];
      }
    }
  }
}

// ---------------------------------------------------------------------------
// Launch. Scratch plan:
//   d_ws : xT (B*N*C bf16 = 25.7MB) | y (B*N*CI bf16 = 12.8MB)  -> 38.5MB
//   d_out: kT | qT | v (3 * 12.85MB = 38.5MB) as scratch until out_kernel
//          overwrites the whole buffer with the final fp32 result.
// Stream ordering gives proj -> attn -> out dependencies; no sync calls.
// ---------------------------------------------------------------------------
extern "C" void kernel_launch(void* const* d_in, const int* in_sizes, int n_in,
                              void* d_out, int out_size, void* d_ws,
                              size_t ws_size, hipStream_t stream) {
  (void)in_sizes;
  (void)n_in;
  (void)out_size;
  (void)ws_size;
  const float* x = (const float*)d_in[0];
  const float* Wk = (const float*)d_in[1];
  const float* bk = (const float*)d_in[2];
  const float* Wq = (const float*)d_in[3];
  const float* bq = (const float*)d_in[4];
  const float* Wv = (const float*)d_in[5];
  const float* bv = (const float*)d_in[6];
  const float* Wo = (const float*)d_in[7];
  const float* bo = (const float*)d_in[8];
  float* out = (float*)d_out;

  bf16* xT = (bf16*)d_ws;                        // B*N*C
  bf16* y = xT + (size_t)Bb * Nn * Cc;           // B*N*CI
  bf16* kT = (bf16*)d_out;                       // B*N*CI
  bf16* qT = kT + (size_t)Bb * Nn * CIi;         // B*N*CI
  bf16* vv = qT + (size_t)Bb * Nn * CIi;         // B*CI*N

  xpose_kernel<<<dim3(Nn / 32, Cc / 32, Bb), 256, 0, stream>>>(x, xT);
  proj_kernel<<<dim3(Nn / 128, CIi / 128, 3 * Bb), 256, 0, stream>>>(
      xT, Wk, Wq, Wv, bk, bq, bv, kT, qT, vv);
  attn_kernel<<<dim3(Nn / 32, Bb), 256, 0, stream>>>(kT, qT, vv, y);
  out_kernel<<<dim3(Cc / 128, Nn / 128, Bb), 256, 0, stream>>>(y, Wo, bo, x,
                                                               out);
}